// Round 3
// baseline (202.457 us; speedup 1.0000x reference)
//
#include <hip/hip_runtime.h>
#include <math.h>
#include <limits.h>

#define ALPHA  0.1f
#define DT     0.01f
#define EPSV   1e-9f
#define DIFF   10.0f
#define HARD_P 1.5707963267948966f

typedef int   v4i __attribute__((ext_vector_type(4)));
typedef float v2f __attribute__((ext_vector_type(2)));

// ---------------------------------------------------------------------------
// Kernel 1: per-node precompute (dense, cheap).
//   g[i] = e^{-i*phase[i]} * (x_i + i*y_i)
//   out[3N:5N] = xy  (xy_dot_old_new)
//   Gsum[i] = 0      (atomic target)
// ---------------------------------------------------------------------------
__global__ void node_pre(const float2* __restrict__ xy,
                         const float*  __restrict__ phase,
                         float2* __restrict__ g,
                         float2* __restrict__ out_xyold,
                         float2* __restrict__ Gsum,
                         int n) {
    int i = blockIdx.x * blockDim.x + threadIdx.x;
    if (i >= n) return;
    float2 p = xy[i];
    float ph = phase[i];
    float s, c;
    sincosf(ph, &s, &c);
    float2 gv;
    gv.x = p.x * c + p.y * s;   // e^{-i ph} * (x + iy)
    gv.y = p.y * c - p.x * s;
    g[i] = gv;
    out_xyold[i] = p;
    float2 z; z.x = 0.f; z.y = 0.f;
    Gsum[i] = z;
}

// Device-scope (L1-bypass) gather: on gfx940+/gfx950 the cache-policy bits
// are SCOPE bits; sc1 = device scope => must bypass the CU-coherent L1.
// (sc0 alone — tested round 2 — is a low scope and still allocates L1.)
__device__ __forceinline__ v2f gather_sc1(const float2* p) {
    v2f r;
    asm volatile("global_load_dwordx2 %0, %1, off sc1"
                 : "=v"(r) : "v"(p));
    return r;
}

// ---------------------------------------------------------------------------
// Kernel 2 (templated): edge-parallel segmented reduction, 4 edges/lane.
// BYPASS_L1=0 -> plain cached gathers; BYPASS_L1=1 -> sc1 device-scope
// gathers. Launched twice on disjoint edge halves => within-probe A/B.
// ---------------------------------------------------------------------------
template<int BYPASS_L1>
__global__ __launch_bounds__(256) void edge_seg4(
        const int*    __restrict__ src,
        const int*    __restrict__ dst,
        const float2* __restrict__ g,
        float* __restrict__ Gsum,
        int n_edges) {
    const int lane = threadIdx.x & 63;
    const int wib  = threadIdx.x >> 6;
    const long wave = (long)blockIdx.x * 4 + wib;        // 4 waves / block
    const long base = wave * 256 + (long)lane * 4;       // this lane's 4 edges

    int   sk[4];
    float vx[4], vy[4];

    if (base + 3 < (long)n_edges) {
        v4i sv = __builtin_nontemporal_load((const v4i*)(src + base));
        v4i dv = __builtin_nontemporal_load((const v4i*)(dst + base));
        sk[0]=sv.x; sk[1]=sv.y; sk[2]=sv.z; sk[3]=sv.w;
        if (BYPASS_L1) {
            v2f G0 = gather_sc1(g + dv.x);
            v2f G1 = gather_sc1(g + dv.y);
            v2f G2 = gather_sc1(g + dv.z);
            v2f G3 = gather_sc1(g + dv.w);
            asm volatile("s_waitcnt vmcnt(0)");
            __builtin_amdgcn_sched_barrier(0);
            vx[0]=G0.x; vy[0]=G0.y; vx[1]=G1.x; vy[1]=G1.y;
            vx[2]=G2.x; vy[2]=G2.y; vx[3]=G3.x; vy[3]=G3.y;
        } else {
            float2 g0 = g[dv.x];
            float2 g1 = g[dv.y];
            float2 g2 = g[dv.z];
            float2 g3 = g[dv.w];
            vx[0]=g0.x; vy[0]=g0.y; vx[1]=g1.x; vy[1]=g1.y;
            vx[2]=g2.x; vy[2]=g2.y; vx[3]=g3.x; vy[3]=g3.y;
        }
    } else {
        #pragma unroll
        for (int j = 0; j < 4; ++j) {
            long e = base + j;
            if (e < (long)n_edges) {
                sk[j] = src[e];
                float2 gd = g[dst[e]];
                vx[j] = gd.x; vy[j] = gd.y;
            } else {
                sk[j] = INT_MAX;    // > all real keys, preserves sortedness
                vx[j] = 0.f; vy[j] = 0.f;
            }
        }
    }

    // ---- local run combine ----
    int   kF = sk[0], rk = sk[0];
    float fx = 0.f, fy = 0.f;            // first-run sum (once closed)
    float rx = vx[0], ry = vy[0];        // current-run sum
    bool  firstClosed = false;
    #pragma unroll
    for (int j = 1; j < 4; ++j) {
        if (sk[j] == rk) {
            rx += vx[j]; ry += vy[j];
        } else {
            if (!firstClosed) { fx = rx; fy = ry; firstClosed = true; }
            else {
                atomicAdd(&Gsum[2*rk],   rx);
                atomicAdd(&Gsum[2*rk+1], ry);
            }
            rk = sk[j]; rx = vx[j]; ry = vy[j];
        }
    }
    const int  kL   = rk;
    const bool pure = !firstClosed;      // whole lane one key

    // ---- wave segmented inclusive scan over (kL, suffix-sum) ----
    float ax = rx, ay = ry;
    int   key = kL;
    #pragma unroll
    for (int off = 1; off < 64; off <<= 1) {
        float px = __shfl_up(ax, off);
        float py = __shfl_up(ay, off);
        int   pk = __shfl_up(key, off);
        if (lane >= off && pk == key) { ax += px; ay += py; }
    }

    // ---- flushes ----
    float pscx = __shfl_up(ax, 1);
    float pscy = __shfl_up(ay, 1);
    int   pKL  = __shfl_up(key, 1);
    int   nKF  = __shfl_down(kF, 1);

    if (!pure) {
        float gx_ = fx, gy_ = fy;
        if (lane > 0 && pKL == kF) { gx_ += pscx; gy_ += pscy; }
        atomicAdd(&Gsum[2*kF],   gx_);
        atomicAdd(&Gsum[2*kF+1], gy_);
    }
    bool endHere = (lane == 63) || (nKF != key);
    if (key != INT_MAX && endHere) {
        atomicAdd(&Gsum[2*key],   ax);
        atomicAdd(&Gsum[2*key+1], ay);
    }
}

// ---------------------------------------------------------------------------
// Kernel 3: dense per-node epilogue (1 thread/node).
// ---------------------------------------------------------------------------
__global__ void node_post(const float2* __restrict__ xy,
                          const float2* __restrict__ xyd,
                          const float*  __restrict__ phase,
                          const float*  __restrict__ w,
                          const float*  __restrict__ amps,
                          const float*  __restrict__ ha,
                          const float2* __restrict__ Gsum,
                          float* __restrict__ out,
                          int n) {
    int i = blockIdx.x * blockDim.x + threadIdx.x;
    if (i >= n) return;
    float2 p   = xy[i];
    float2 pdv = xyd[i];
    float x = p.x, y = p.y;
    float xd = pdv.x, yd = pdv.y;

    float r2 = x*x + y*y;
    float a = ALPHA * (1.0f - r2*r2);
    float h = ha[i];
    float zeta = 1.0f - h * ((xd + EPSV) / (fabsf(xd) + EPSV));
    float b = w[i] / (zeta + EPSV);
    float kx = a*x - b*y;
    float ky = b*x + a*y;

    float2 gv = Gsum[i];
    float s, c;
    sincosf(phase[i], &s, &c);
    float sumx = c*gv.x - s*gv.y;   // rotate by e^{+i*phase}
    float sumy = s*gv.x + c*gv.y;

    float xdot = fminf(fmaxf(kx + sumx, xd - DIFF), xd + DIFF);
    float ydot = fminf(fmaxf(ky + sumy, yd - DIFF), yd + DIFF);
    float xn = x + xdot * DT;
    float yn = y + ydot * DT;

    float ang = fminf(fmaxf(amps[i] * yn, -HARD_P), HARD_P);

    out[i] = ang;
    float2* xy_new = (float2*)(out + n);
    float2 v; v.x = xn; v.y = yn;
    xy_new[i] = v;
}

extern "C" void kernel_launch(void* const* d_in, const int* in_sizes, int n_in,
                              void* d_out, int out_size, void* d_ws, size_t ws_size,
                              hipStream_t stream) {
    const float2* xy    = (const float2*)d_in[0];
    const float2* xyd   = (const float2*)d_in[1];
    const float*  phase = (const float*)d_in[2];
    const float*  w     = (const float*)d_in[3];
    const float*  amps  = (const float*)d_in[4];
    const float*  ha    = (const float*)d_in[5];
    const int*    esrc  = (const int*)d_in[6];
    const int*    edst  = (const int*)d_in[7];

    const int n       = in_sizes[2];
    const int n_edges = in_sizes[6];

    float* out = (float*)d_out;

    // ws: g float2[n] | Gsum float2[n]
    float2* g    = (float2*)d_ws;
    float2* Gsum = (float2*)((char*)d_ws + (size_t)n * sizeof(float2));

    const int B = 256;
    node_pre<<<(n + B - 1) / B, B, 0, stream>>>(
        xy, phase, g, (float2*)(out + (size_t)3 * n), Gsum, n);

    // A/B split: first half plain (cached), second half sc1 (L1-bypass).
    // Each sub-range stays sorted; boundary nodes are handled correctly
    // because all flushes are atomic.
    int n_blocks   = (n_edges + 1023) / 1024;     // 1024 edges per block
    int blocks_a   = n_blocks / 2;
    long edges_a   = (long)blocks_a * 1024;       // multiple of tile size
    int n_edges_a  = (int)edges_a;
    int n_edges_b  = n_edges - n_edges_a;
    int blocks_b   = (n_edges_b + 1023) / 1024;

    if (blocks_a > 0)
        edge_seg4<0><<<blocks_a, B, 0, stream>>>(esrc, edst, g, (float*)Gsum,
                                                 n_edges_a);
    if (blocks_b > 0)
        edge_seg4<1><<<blocks_b, B, 0, stream>>>(esrc + edges_a, edst + edges_a,
                                                 g, (float*)Gsum, n_edges_b);

    node_post<<<(n + B - 1) / B, B, 0, stream>>>(
        xy, xyd, phase, w, amps, ha, Gsum, out, n);
}

// Round 4
// 198.729 us; speedup vs baseline: 1.0188x; 1.0188x over previous
//
#include <hip/hip_runtime.h>
#include <math.h>
#include <limits.h>

#define ALPHA  0.1f
#define DT     0.01f
#define EPSV   1e-9f
#define DIFF   10.0f
#define HARD_P 1.5707963267948966f

typedef int v4i __attribute__((ext_vector_type(4)));

// ---------------------------------------------------------------------------
// Kernel 1: per-node precompute (dense, cheap).
//   g[i] = e^{-i*phase[i]} * (x_i + i*y_i)
//   out[3N:5N] = xy  (xy_dot_old_new)
//   Gsum[i] = 0      (atomic target)
// ---------------------------------------------------------------------------
__global__ void node_pre(const float2* __restrict__ xy,
                         const float*  __restrict__ phase,
                         float2* __restrict__ g,
                         float2* __restrict__ out_xyold,
                         float2* __restrict__ Gsum,
                         int n) {
    int i = blockIdx.x * blockDim.x + threadIdx.x;
    if (i >= n) return;
    float2 p = xy[i];
    float ph = phase[i];
    float s, c;
    sincosf(ph, &s, &c);
    float2 gv;
    gv.x = p.x * c + p.y * s;   // e^{-i ph} * (x + iy)
    gv.y = p.y * c - p.x * s;
    g[i] = gv;
    out_xyold[i] = p;
    float2 z; z.x = 0.f; z.y = 0.f;
    Gsum[i] = z;
}

// ---------------------------------------------------------------------------
// Kernel 2: edge-parallel segmented reduction, 4 edges per lane.
// SESSION CEILING NOTE: the 12.8M random 8B gathers of g[dst] run at a fixed
// 166 G req/s (0.27 req/cy/CU). Measured invariant to: occupancy 71%<->31%,
// MLP 4<->8 per lane, cache policy default/sc0/sc1, dispatch split, and
// persistent-wave software pipelining. Wall = line-granular L2 return path
// (~64B/line for 8B used => ~10.6 TB/s effective). Do not re-litigate with
// policy bits or occupancy knobs; only an edge reordering (impossible here:
// workspace is re-poisoned every iteration) would move it.
// ---------------------------------------------------------------------------
__global__ __launch_bounds__(256) void edge_seg4(
        const int*    __restrict__ src,
        const int*    __restrict__ dst,
        const float2* __restrict__ g,
        float* __restrict__ Gsum,
        int n_edges) {
    const int lane = threadIdx.x & 63;
    const int wib  = threadIdx.x >> 6;
    const long wave = (long)blockIdx.x * 4 + wib;        // 4 waves / block
    const long base = wave * 256 + (long)lane * 4;       // this lane's 4 edges

    int   sk[4];
    float vx[4], vy[4];

    if (base + 3 < (long)n_edges) {
        v4i sv = __builtin_nontemporal_load((const v4i*)(src + base));
        v4i dv = __builtin_nontemporal_load((const v4i*)(dst + base));
        sk[0]=sv.x; sk[1]=sv.y; sk[2]=sv.z; sk[3]=sv.w;
        // 4 independent L2-resident gathers in flight
        float2 g0 = g[dv.x];
        float2 g1 = g[dv.y];
        float2 g2 = g[dv.z];
        float2 g3 = g[dv.w];
        vx[0]=g0.x; vy[0]=g0.y; vx[1]=g1.x; vy[1]=g1.y;
        vx[2]=g2.x; vy[2]=g2.y; vx[3]=g3.x; vy[3]=g3.y;
    } else {
        #pragma unroll
        for (int j = 0; j < 4; ++j) {
            long e = base + j;
            if (e < (long)n_edges) {
                sk[j] = src[e];
                float2 gd = g[dst[e]];
                vx[j] = gd.x; vy[j] = gd.y;
            } else {
                sk[j] = INT_MAX;    // > all real keys, preserves sortedness
                vx[j] = 0.f; vy[j] = 0.f;
            }
        }
    }

    // ---- local run combine ----
    int   kF = sk[0], rk = sk[0];
    float fx = 0.f, fy = 0.f;            // first-run sum (once closed)
    float rx = vx[0], ry = vy[0];        // current-run sum
    bool  firstClosed = false;
    #pragma unroll
    for (int j = 1; j < 4; ++j) {
        if (sk[j] == rk) {
            rx += vx[j]; ry += vy[j];
        } else {
            if (!firstClosed) { fx = rx; fy = ry; firstClosed = true; }
            else {
                // interior complete run (rare: needs 2+ boundaries in 4 edges)
                atomicAdd(&Gsum[2*rk],   rx);
                atomicAdd(&Gsum[2*rk+1], ry);
            }
            rk = sk[j]; rx = vx[j]; ry = vy[j];
        }
    }
    const int  kL   = rk;
    const bool pure = !firstClosed;      // whole lane one key

    // ---- wave segmented inclusive scan over (kL, suffix-sum) ----
    // Correct because keys are sorted: equal kL at distance implies all
    // intervening lanes are pure with the same key.
    float ax = rx, ay = ry;
    int   key = kL;
    #pragma unroll
    for (int off = 1; off < 64; off <<= 1) {
        float px = __shfl_up(ax, off);
        float py = __shfl_up(ay, off);
        int   pk = __shfl_up(key, off);
        if (lane >= off && pk == key) { ax += px; ay += py; }
    }

    // ---- flushes ----
    float pscx = __shfl_up(ax, 1);
    float pscy = __shfl_up(ay, 1);
    int   pKL  = __shfl_up(key, 1);
    int   nKF  = __shfl_down(kF, 1);

    // (1) non-pure lane closes its first run (absorbing carry from prev lanes)
    if (!pure) {                          // kF < kL <= INT_MAX, so kF valid
        float gx_ = fx, gy_ = fy;
        if (lane > 0 && pKL == kF) { gx_ += pscx; gy_ += pscy; }
        atomicAdd(&Gsum[2*kF],   gx_);
        atomicAdd(&Gsum[2*kF+1], gy_);
    }
    // (2) last run ends at a lane boundary (or wave end): flush scan result
    bool endHere = (lane == 63) || (nKF != key);
    if (key != INT_MAX && endHere) {
        atomicAdd(&Gsum[2*key],   ax);
        atomicAdd(&Gsum[2*key+1], ay);
    }
}

// ---------------------------------------------------------------------------
// Kernel 3: dense per-node epilogue (1 thread/node).
// ---------------------------------------------------------------------------
__global__ void node_post(const float2* __restrict__ xy,
                          const float2* __restrict__ xyd,
                          const float*  __restrict__ phase,
                          const float*  __restrict__ w,
                          const float*  __restrict__ amps,
                          const float*  __restrict__ ha,
                          const float2* __restrict__ Gsum,
                          float* __restrict__ out,
                          int n) {
    int i = blockIdx.x * blockDim.x + threadIdx.x;
    if (i >= n) return;
    float2 p   = xy[i];
    float2 pdv = xyd[i];
    float x = p.x, y = p.y;
    float xd = pdv.x, yd = pdv.y;

    float r2 = x*x + y*y;
    float a = ALPHA * (1.0f - r2*r2);
    float h = ha[i];
    float zeta = 1.0f - h * ((xd + EPSV) / (fabsf(xd) + EPSV));
    float b = w[i] / (zeta + EPSV);
    float kx = a*x - b*y;
    float ky = b*x + a*y;

    float2 gv = Gsum[i];
    float s, c;
    sincosf(phase[i], &s, &c);
    float sumx = c*gv.x - s*gv.y;   // rotate by e^{+i*phase}
    float sumy = s*gv.x + c*gv.y;

    float xdot = fminf(fmaxf(kx + sumx, xd - DIFF), xd + DIFF);
    float ydot = fminf(fmaxf(ky + sumy, yd - DIFF), yd + DIFF);
    float xn = x + xdot * DT;
    float yn = y + ydot * DT;

    float ang = fminf(fmaxf(amps[i] * yn, -HARD_P), HARD_P);

    out[i] = ang;
    float2* xy_new = (float2*)(out + n);
    float2 v; v.x = xn; v.y = yn;
    xy_new[i] = v;
}

extern "C" void kernel_launch(void* const* d_in, const int* in_sizes, int n_in,
                              void* d_out, int out_size, void* d_ws, size_t ws_size,
                              hipStream_t stream) {
    const float2* xy    = (const float2*)d_in[0];
    const float2* xyd   = (const float2*)d_in[1];
    const float*  phase = (const float*)d_in[2];
    const float*  w     = (const float*)d_in[3];
    const float*  amps  = (const float*)d_in[4];
    const float*  ha    = (const float*)d_in[5];
    const int*    esrc  = (const int*)d_in[6];
    const int*    edst  = (const int*)d_in[7];

    const int n       = in_sizes[2];
    const int n_edges = in_sizes[6];

    float* out = (float*)d_out;

    // ws: g float2[n] | Gsum float2[n]
    float2* g    = (float2*)d_ws;
    float2* Gsum = (float2*)((char*)d_ws + (size_t)n * sizeof(float2));

    const int B = 256;
    node_pre<<<(n + B - 1) / B, B, 0, stream>>>(
        xy, phase, g, (float2*)(out + (size_t)3 * n), Gsum, n);

    // each block: 4 waves x 256 edges = 1024 edges
    int n_blocks = (n_edges + 1023) / 1024;
    edge_seg4<<<n_blocks, B, 0, stream>>>(esrc, edst, g, (float*)Gsum, n_edges);

    node_post<<<(n + B - 1) / B, B, 0, stream>>>(
        xy, xyd, phase, w, amps, ha, Gsum, out, n);
}